// Round 1
// baseline (326.181 us; speedup 1.0000x reference)
//
#include <hip/hip_runtime.h>
#include <hip/hip_bf16.h>

#define N_NODES 8192
#define D_DIM   256

typedef __attribute__((ext_vector_type(8))) short short8v;   // 8 x bf16 (4 VGPR)
typedef __attribute__((ext_vector_type(4))) float f32x4;

__device__ __forceinline__ float artanh_clip(float x) {
    x = fminf(x, 1.0f - 1e-7f);
    return 0.5f * logf((1.0f + x) / (1.0f - x));
}

__device__ __forceinline__ ushort4 cvt4_bf16(float4 v) {
    ushort4 b;
    b.x = __bfloat16_as_ushort(__float2bfloat16(v.x));
    b.y = __bfloat16_as_ushort(__float2bfloat16(v.y));
    b.z = __bfloat16_as_ushort(__float2bfloat16(v.z));
    b.w = __bfloat16_as_ushort(__float2bfloat16(v.w));
    return b;
}

// ---------------- K0: hyp_bias = proj(expmap0(bias)), plus b2 = ||hb||^2 ----
__global__ void k0_bias(const float* __restrict__ bias, float* __restrict__ hbg) {
    __shared__ float sp[4];
    __shared__ float s_g;
    int t = threadIdx.x;
    float u = bias[t];
    float v = u * u;
    #pragma unroll
    for (int o = 1; o < 64; o <<= 1) v += __shfl_xor(v, o);
    if ((t & 63) == 0) sp[t >> 6] = v;
    __syncthreads();
    if (t == 0) {
        float s  = sp[0] + sp[1] + sp[2] + sp[3];
        float un = fmaxf(sqrtf(s), 1e-15f);
        float t1 = tanhf(un);
        s_g = (t1 > 0.996f) ? (0.996f / un) : (t1 / un);
    }
    __syncthreads();
    float hb = s_g * u;
    hbg[t] = hb;
    float v2 = hb * hb;
    #pragma unroll
    for (int o = 1; o < 64; o <<= 1) v2 += __shfl_xor(v2, o);
    if ((t & 63) == 0) sp[t >> 6] = v2;
    __syncthreads();
    if (t == 0) hbg[256] = sp[0] + sp[1] + sp[2] + sp[3];
}

// ---------------- K1: HypLinear + logmap0 -> xtT (bf16, transposed [D][N]) --
// block = 256 threads, 32 rows per block; thread t owns output dim d = t.
__global__ __launch_bounds__(256) void k1_hyplinear(
    const float* __restrict__ x, const float* __restrict__ W,
    const float* __restrict__ hbg, __hip_bfloat16* __restrict__ xtT)
{
    __shared__ __align__(16) float sx[32][260];   // x tile, then reused for mx
    __shared__ __align__(16) float sw[256][68];   // W k-chunk [d][64]
    __shared__ float s_xn[32], s_P[32], s_Q[32];
    __shared__ float s_hb[256];
    __shared__ float s_b2;

    const int t  = threadIdx.x;
    const int r0 = blockIdx.x * 32;

    {   // load x tile: row t>>3, cols (t&7)*32 .. +31
        int row = t >> 3, c0 = (t & 7) * 32;
        const float4* src = (const float4*)(x + (r0 + row) * 256 + c0);
        float4* dst = (float4*)(&sx[row][c0]);
        #pragma unroll
        for (int i = 0; i < 8; i++) dst[i] = src[i];
    }
    s_hb[t] = hbg[t];
    if (t == 0) s_b2 = hbg[256];
    __syncthreads();

    {   // per-row ||x||^2  (8 threads per row)
        int r = t >> 3, j = t & 7;
        float s2 = 0.f;
        #pragma unroll
        for (int i = 0; i < 32; i++) { float v = sx[r][j * 32 + i]; s2 += v * v; }
        s2 += __shfl_xor(s2, 1); s2 += __shfl_xor(s2, 2); s2 += __shfl_xor(s2, 4);
        if (j == 0) s_xn[r] = s2;
    }

    // mx[r][t] = sum_k x[r][k] * W[t][k]   (f32, W staged in 64-wide k-chunks)
    float acc[32];
    #pragma unroll
    for (int r = 0; r < 32; r++) acc[r] = 0.f;

    for (int kc = 0; kc < 4; kc++) {
        __syncthreads();
        int d0 = t >> 4, j4 = (t & 15) * 4;
        #pragma unroll
        for (int i = 0; i < 16; i++) {
            int d = d0 + i * 16;
            float4 w4 = *(const float4*)(W + d * 256 + kc * 64 + j4);
            *(float4*)(&sw[d][j4]) = w4;
        }
        __syncthreads();
        #pragma unroll
        for (int kk = 0; kk < 16; kk++) {
            float4 w4 = *(const float4*)(&sw[t][kk * 4]);
            #pragma unroll
            for (int r = 0; r < 32; r++) {
                float4 x4 = *(const float4*)(&sx[r][kc * 64 + kk * 4]);
                acc[r] += w4.x * x4.x + w4.y * x4.y + w4.z * x4.z + w4.w * x4.w;
            }
        }
    }
    __syncthreads();
    #pragma unroll
    for (int r = 0; r < 32; r++) sx[r][t] = acc[r];   // reuse sx as mx tile
    __syncthreads();

    {   // per-row sumsq(mx), dot(mx, hb) -> scalar chain -> P, Q
        int r = t >> 3, j = t & 7;
        float s2 = 0.f, dt = 0.f;
        #pragma unroll
        for (int i = 0; i < 32; i++) {
            float v = sx[r][j * 32 + i];
            s2 += v * v;
            dt += v * s_hb[j * 32 + i];
        }
        s2 += __shfl_xor(s2, 1); s2 += __shfl_xor(s2, 2); s2 += __shfl_xor(s2, 4);
        dt += __shfl_xor(dt, 1); dt += __shfl_xor(dt, 2); dt += __shfl_xor(dt, 4);
        if (j == 0) {
            float b2  = s_b2;
            float xn  = fmaxf(sqrtf(s_xn[r]), 1e-15f);
            float mx2 = s2;
            float mxn = fmaxf(sqrtf(mx2), 1e-15f);
            // mobius_matvec: mv = fr * mx
            float at = artanh_clip(xn);
            float tt = tanhf(mxn / xn * at);
            float fr = tt / mxn;
            // proj(mv): ||mv|| = tt
            if (tt > 0.996f) fr = 0.996f / mxn;
            float mvn = fminf(tt, 0.996f);
            float x2  = mvn * mvn;
            // mobius_add(res, hb): h = (A*fr*mx + B*hb)/den
            float xy  = fr * dt;
            float cA  = 1.0f + 2.0f * xy + b2;
            float cB  = 1.0f - x2;
            float den = fmaxf(1.0f + 2.0f * xy + x2 * b2, 1e-15f);
            float P0 = cA * fr / den;
            float Q0 = cB / den;
            // ||h||^2 from scalars; proj; logmap0
            float hn = sqrtf(fmaxf(P0 * P0 * mx2 + 2.0f * P0 * Q0 * dt + Q0 * Q0 * b2, 0.0f));
            hn = fmaxf(hn, 1e-15f);
            float pf  = (hn > 0.996f) ? (0.996f / hn) : 1.0f;
            float hnp = fminf(hn, 0.996f);
            float lam = artanh_clip(hnp) / hnp;
            s_P[r] = lam * pf * P0;
            s_Q[r] = lam * pf * Q0;
        }
    }
    __syncthreads();

    {   // xt[r][t] = P[r]*mx[r][t] + Q[r]*hb[t]; write transposed: xtT[t][r0+r]
        float hb = s_hb[t];
        unsigned int pk[16];
        #pragma unroll
        for (int r = 0; r < 32; r += 2) {
            float a0 = s_P[r]     * acc[r]     + s_Q[r]     * hb;
            float a1 = s_P[r + 1] * acc[r + 1] + s_Q[r + 1] * hb;
            unsigned int lo = (unsigned int)__bfloat16_as_ushort(__float2bfloat16(a0));
            unsigned int hi = (unsigned int)__bfloat16_as_ushort(__float2bfloat16(a1));
            pk[r >> 1] = lo | (hi << 16);
        }
        uint4* dst = (uint4*)(xtT + t * 8192 + r0);
        #pragma unroll
        for (int i = 0; i < 4; i++)
            dst[i] = make_uint4(pk[4 * i], pk[4 * i + 1], pk[4 * i + 2], pk[4 * i + 3]);
    }
}

// ---------------- K2: fused adj-copy + (adj @ xt) MFMA + hyperbolic epilogue -
// grid 256, block 512 (8 waves). BM=32, BN=256, BK=64.
// wave = (wr, wc): wr in {0,1} splits K (kk-half), wc in {0..3} splits cols.
__global__ __launch_bounds__(512) void k2_agg(
    const float* __restrict__ adj,
    const __hip_bfloat16* __restrict__ xtT,
    float* __restrict__ out_h,
    float* __restrict__ out_adj)
{
    __shared__ __align__(16) __hip_bfloat16 As[2][32][72];  // A tile, dbuf, +8 pad
    __shared__ __align__(16) float sup[32][260];
    __shared__ float sF[32];

    const int t    = threadIdx.x;
    const int lane = t & 63;
    const int wave = t >> 6;
    const int wr   = wave >> 2;   // K half
    const int wc   = wave & 3;    // col quarter
    const int m0   = blockIdx.x * 32;

    const int srow = t >> 4;          // staging: row 0..31
    const int scol = (t & 15) * 4;    // staging: 4 floats

    f32x4 acc[2][4];
    #pragma unroll
    for (int i = 0; i < 2; i++)
        #pragma unroll
        for (int j = 0; j < 4; j++) acc[i][j] = (f32x4){0.f, 0.f, 0.f, 0.f};

    const int arow = lane & 15;
    const int acol = wr * 32 + 8 * (lane >> 4);
    const int brow = wc * 64 + (lane & 15);
    const int bk   = wr * 32 + 8 * (lane >> 4);
    const __hip_bfloat16* bptr = xtT + brow * 8192 + bk;

    {   // prologue: stage tile 0 (and emit adj passthrough)
        int g = (m0 + srow) * 8192 + scol;
        float4 v = *(const float4*)(adj + g);
        *(float4*)(out_adj + g) = v;
        *(ushort4*)(&As[0][srow][scol]) = cvt4_bf16(v);
    }
    __syncthreads();

    int cur = 0;
    for (int kt = 0; kt < 128; kt++) {
        const int k0 = kt * 64;
        // T14: issue next A-tile loads early
        float4 v;
        const bool has_next = (kt + 1 < 128);
        if (has_next)
            v = *(const float4*)(adj + (m0 + srow) * 8192 + k0 + 64 + scol);

        // B fragments: direct 16B contiguous global loads from xtT (L2-resident)
        const __hip_bfloat16* bb = bptr + k0;
        short8v b0 = *(const short8v*)(bb);
        short8v b1 = *(const short8v*)(bb + 16 * 8192);
        short8v b2 = *(const short8v*)(bb + 32 * 8192);
        short8v b3 = *(const short8v*)(bb + 48 * 8192);
        // A fragments from LDS
        short8v a0 = *(const short8v*)(&As[cur][arow][acol]);
        short8v a1 = *(const short8v*)(&As[cur][16 + arow][acol]);

        acc[0][0] = __builtin_amdgcn_mfma_f32_16x16x32_bf16(a0, b0, acc[0][0], 0, 0, 0);
        acc[0][1] = __builtin_amdgcn_mfma_f32_16x16x32_bf16(a0, b1, acc[0][1], 0, 0, 0);
        acc[0][2] = __builtin_amdgcn_mfma_f32_16x16x32_bf16(a0, b2, acc[0][2], 0, 0, 0);
        acc[0][3] = __builtin_amdgcn_mfma_f32_16x16x32_bf16(a0, b3, acc[0][3], 0, 0, 0);
        acc[1][0] = __builtin_amdgcn_mfma_f32_16x16x32_bf16(a1, b0, acc[1][0], 0, 0, 0);
        acc[1][1] = __builtin_amdgcn_mfma_f32_16x16x32_bf16(a1, b1, acc[1][1], 0, 0, 0);
        acc[1][2] = __builtin_amdgcn_mfma_f32_16x16x32_bf16(a1, b2, acc[1][2], 0, 0, 0);
        acc[1][3] = __builtin_amdgcn_mfma_f32_16x16x32_bf16(a1, b3, acc[1][3], 0, 0, 0);

        if (has_next) {   // write-late: adj passthrough + bf16 -> LDS (other buffer)
            int g = (m0 + srow) * 8192 + k0 + 64 + scol;
            *(float4*)(out_adj + g) = v;
            *(ushort4*)(&As[cur ^ 1][srow][scol]) = cvt4_bf16(v);
        }
        __syncthreads();
        cur ^= 1;
    }

    // reduce the two K-half partials into sup (C layout: col=lane&15, row=(lane>>4)*4+q)
    const int crow0 = 4 * (lane >> 4);
    const int ccol  = lane & 15;
    if (wr == 0) {
        #pragma unroll
        for (int mf = 0; mf < 2; mf++)
            #pragma unroll
            for (int nf = 0; nf < 4; nf++)
                #pragma unroll
                for (int q = 0; q < 4; q++)
                    sup[mf * 16 + crow0 + q][wc * 64 + nf * 16 + ccol] = acc[mf][nf][q];
    }
    __syncthreads();
    if (wr == 1) {
        #pragma unroll
        for (int mf = 0; mf < 2; mf++)
            #pragma unroll
            for (int nf = 0; nf < 4; nf++)
                #pragma unroll
                for (int q = 0; q < 4; q++)
                    sup[mf * 16 + crow0 + q][wc * 64 + nf * 16 + ccol] += acc[mf][nf][q];
    }
    __syncthreads();

    {   // per-row: sumsq(all), sumsq(relu) -> scalar chain -> F
        int r = t >> 4, j = t & 15;
        float s2 = 0.f, sp = 0.f;
        #pragma unroll
        for (int i = 0; i < 16; i++) {
            float vv = sup[r][j * 16 + i];
            s2 += vv * vv;
            float vp = fmaxf(vv, 0.f);
            sp += vp * vp;
        }
        s2 += __shfl_xor(s2, 1); s2 += __shfl_xor(s2, 2); s2 += __shfl_xor(s2, 4); s2 += __shfl_xor(s2, 8);
        sp += __shfl_xor(sp, 1); sp += __shfl_xor(sp, 2); sp += __shfl_xor(sp, 4); sp += __shfl_xor(sp, 8);
        if (j == 0) {
            float ns = fmaxf(sqrtf(s2), 1e-15f);
            float t1 = tanhf(ns);
            float alpha = (t1 > 0.996f) ? (0.996f / ns) : (t1 / ns);   // expmap0+proj
            float nh = fminf(t1, 0.996f);
            float beta = artanh_clip(nh) / nh;                          // logmap0
            float ba = beta * alpha;
            float nxt = fmaxf(ba * sqrtf(sp), 1e-15f);                  // ||relu(xt)||
            float t2 = tanhf(nxt);
            float delta = (t2 > 0.996f) ? (0.996f / nxt) : (t2 / nxt);  // expmap0+proj
            sF[r] = delta * ba;
        }
    }
    __syncthreads();
    {   // h[m0+r][:] = F[r] * relu(support)
        int r = t >> 4, j = t & 15;
        float F = sF[r];
        float4* dst = (float4*)(out_h + (m0 + r) * 256 + j * 16);
        #pragma unroll
        for (int i = 0; i < 4; i++) {
            float4 o;
            o.x = F * fmaxf(sup[r][j * 16 + 4 * i + 0], 0.f);
            o.y = F * fmaxf(sup[r][j * 16 + 4 * i + 1], 0.f);
            o.z = F * fmaxf(sup[r][j * 16 + 4 * i + 2], 0.f);
            o.w = F * fmaxf(sup[r][j * 16 + 4 * i + 3], 0.f);
            dst[i] = o;
        }
    }
}

extern "C" void kernel_launch(void* const* d_in, const int* in_sizes, int n_in,
                              void* d_out, int out_size, void* d_ws, size_t ws_size,
                              hipStream_t stream)
{
    const float* x    = (const float*)d_in[0];
    const float* adj  = (const float*)d_in[1];
    const float* W    = (const float*)d_in[2];
    const float* bias = (const float*)d_in[3];

    float* out_h   = (float*)d_out;
    float* out_adj = out_h + (size_t)N_NODES * D_DIM;

    __hip_bfloat16* xtT = (__hip_bfloat16*)d_ws;                       // [256][8192] bf16 = 4 MB
    float* hbg = (float*)((char*)d_ws + (size_t)D_DIM * N_NODES * 2);  // hb[256] + b2

    k0_bias<<<1, 256, 0, stream>>>(bias, hbg);
    k1_hyplinear<<<256, 256, 0, stream>>>(x, W, hbg, xtT);
    k2_agg<<<256, 512, 0, stream>>>(adj, xtT, out_h, out_adj);
}